// Round 2
// baseline (609.796 us; speedup 1.0000x reference)
//
#include <hip/hip_runtime.h>
#include <hip/hip_bf16.h>

#define B_ 16
#define S_ 4096
#define E_ 768
#define H_ 4
#define A_ 128

constexpr float ALPHA = 0.2f;
constexpr float LOG2E = 1.44269504088896340736f;

typedef __attribute__((ext_vector_type(4))) float f32x4;
typedef __attribute__((ext_vector_type(8))) short bf16x8;

__device__ __forceinline__ unsigned short f2bf(float f) {
    union { float f; unsigned int u; } v;
    v.f = f;
    unsigned int u = v.u;
    unsigned int r = (u + 0x7FFFu + ((u >> 16) & 1u)) >> 16;
    return (unsigned short)r;
}

// ---------------------------------------------------------------------------
// prep1: W1 [h][e][a] f32 -> W1T [h][a][e] bf16   (LDS tile transpose, coalesced)
// ---------------------------------------------------------------------------
__global__ __launch_bounds__(256) void k_prep1(const float* __restrict__ w1,
                                               unsigned short* __restrict__ w1t) {
    __shared__ unsigned short t[64 * 65];
    int bid = blockIdx.x;              // 96 = 4h * 12e-tiles * 2a-tiles
    int ta = bid & 1;
    int te = (bid >> 1) % 12;
    int h  = bid / 24;
    const float* src = w1 + (size_t)h * E_ * A_;
    unsigned short* dst = w1t + (size_t)h * A_ * E_;
    int tid = threadIdx.x;
#pragma unroll
    for (int it = 0; it < 16; ++it) {
        int idx = it * 256 + tid;
        int r = idx >> 6, c = idx & 63;           // r: e-local, c: a-local
        t[r * 65 + c] = f2bf(src[(size_t)(te * 64 + r) * A_ + ta * 64 + c]);
    }
    __syncthreads();
#pragma unroll
    for (int it = 0; it < 16; ++it) {
        int idx = it * 256 + tid;
        int a = idx >> 6, e = idx & 63;           // write coalesced along e
        dst[(size_t)(ta * 64 + a) * E_ + te * 64 + e] = t[e * 65 + a];
    }
}

// ---------------------------------------------------------------------------
// prep2: W2 [h][a][e] f32 -> W2T [h][e][a] bf16, pre-scaled by log2(e)
// (b2 is dropped entirely: constant over s => cancels in softmax over s)
// ---------------------------------------------------------------------------
__global__ __launch_bounds__(256) void k_prep2(const float* __restrict__ w2,
                                               unsigned short* __restrict__ w2t) {
    __shared__ unsigned short t[64 * 65];
    int bid = blockIdx.x;              // 96
    int te = bid % 12;
    int ta = (bid / 12) & 1;
    int h  = bid / 24;
    const float* src = w2 + (size_t)h * A_ * E_;
    unsigned short* dst = w2t + (size_t)h * E_ * A_;
    int tid = threadIdx.x;
#pragma unroll
    for (int it = 0; it < 16; ++it) {
        int idx = it * 256 + tid;
        int r = idx >> 6, c = idx & 63;           // r: a-local, c: e-local
        t[r * 65 + c] = f2bf(src[(size_t)(ta * 64 + r) * E_ + te * 64 + c] * LOG2E);
    }
    __syncthreads();
#pragma unroll
    for (int it = 0; it < 16; ++it) {
        int idx = it * 256 + tid;
        int e = idx >> 6, a = idx & 63;           // write coalesced along a
        dst[(size_t)(te * 64 + e) * A_ + ta * 64 + a] = t[a * 65 + e];
    }
}

// ---------------------------------------------------------------------------
// fused: per block (b, st s-tile of 128, h):
//   GEMM1: h_tile[128s][128a] = leakyrelu(x W1 + b1)  (bf16 MFMA, LDS-staged)
//   h_tile -> LDS (XOR-swizzled)
//   stage2: waves split e (32 cols each); et-pairs; A=W2(rows=e) B=h(cols=s)
//   => lane holds 4 consecutive e per s-col; p=exp2(logit'); z+=p; o+=p*x (f32x4)
//   writes per-(b,h,e) partial (z,o) for this s-chunk.
// ---------------------------------------------------------------------------
__global__ __launch_bounds__(256) void k_fused(
    const float* __restrict__ x, const unsigned short* __restrict__ w1t,
    const float* __restrict__ b1, const unsigned short* __restrict__ w2t,
    float* __restrict__ part_z, float* __restrict__ part_o) {

    // XCD-grouped bijective remap (2048 = 8 * 256): consecutive wid share an XCD;
    // 4 consecutive wid (the 4 h's) share the same x tile -> L2 locality.
    int bid = blockIdx.x;
    int wid = (bid & 7) * 256 + (bid >> 3);
    const int h  = wid & 3;
    const int st = (wid >> 2) & 31;
    const int b  = wid >> 7;
    const int s0 = st * 128;

    const int tid = threadIdx.x;
    const int wave = tid >> 6, lane = tid & 63;
    const int lr = lane & 15, lg = lane >> 4;

    __shared__ unsigned short smem[16384];   // 32KB: staging A|B, then h-tile
    unsigned short* stg_a = smem;
    unsigned short* stg_b = smem + 8192;

    f32x4 acc[2][8];
#pragma unroll
    for (int i = 0; i < 2; ++i)
#pragma unroll
        for (int j = 0; j < 8; ++j) acc[i][j] = (f32x4)0.0f;

    const float* xb = x + ((size_t)b * S_ + s0) * E_;
    const unsigned short* w1h = w1t + (size_t)h * A_ * E_;

#pragma unroll 1
    for (int e0 = 0; e0 < E_; e0 += 64) {
        __syncthreads();
#pragma unroll
        for (int it = 0; it < 4; ++it) {
            int ci = tid + it * 256;
            int r = ci >> 3, c = ci & 7;
            int byte = (r * 128 + c * 16) ^ ((r & 7) << 4);
            const float* ap = xb + (size_t)r * E_ + e0 + c * 8;
            f32x4 v0 = *(const f32x4*)ap;
            f32x4 v1 = *(const f32x4*)(ap + 4);
            bf16x8 av;
#pragma unroll
            for (int j = 0; j < 4; ++j) {
                av[j]     = (short)f2bf(v0[j]);
                av[4 + j] = (short)f2bf(v1[j]);
            }
            *(bf16x8*)((char*)stg_a + byte) = av;
            *(bf16x8*)((char*)stg_b + byte) = *(const bf16x8*)(w1h + (size_t)r * E_ + e0 + c * 8);
        }
        __syncthreads();
#pragma unroll
        for (int kk = 0; kk < 2; ++kk) {
            bf16x8 afr[2], bfr[8];
#pragma unroll
            for (int sf = 0; sf < 2; ++sf) {
                int row = wave * 32 + sf * 16 + lr;
                afr[sf] = *(const bf16x8*)((char*)stg_a + ((row * 128 + kk * 64 + lg * 16) ^ ((row & 7) << 4)));
            }
#pragma unroll
            for (int nf = 0; nf < 8; ++nf) {
                int row = nf * 16 + lr;
                bfr[nf] = *(const bf16x8*)((char*)stg_b + ((row * 128 + kk * 64 + lg * 16) ^ ((row & 7) << 4)));
            }
#pragma unroll
            for (int nf = 0; nf < 8; ++nf) {
                acc[0][nf] = __builtin_amdgcn_mfma_f32_16x16x32_bf16(afr[0], bfr[nf], acc[0][nf], 0, 0, 0);
                acc[1][nf] = __builtin_amdgcn_mfma_f32_16x16x32_bf16(afr[1], bfr[nf], acc[1][nf], 0, 0, 0);
            }
        }
    }

    __syncthreads();                         // frag reads done; smem becomes h-tile
    unsigned short* hmt = smem;              // [128 s][128 a], XOR-swizzled
#pragma unroll
    for (int nf = 0; nf < 8; ++nf) {
        float bias = b1[h * A_ + nf * 16 + lr];
#pragma unroll
        for (int sf = 0; sf < 2; ++sf) {
#pragma unroll
            for (int j = 0; j < 4; ++j) {
                float v = acc[sf][nf][j] + bias;
                v = v >= 0.0f ? v : ALPHA * v;
                int srow = wave * 32 + sf * 16 + lg * 4 + j;
                int a = nf * 16 + lr;
                int byte = (srow * 256 + a * 2) ^ ((srow & 7) << 4);
                *(unsigned short*)((char*)hmt + byte) = f2bf(v);
            }
        }
    }
    __syncthreads();

    // ---- stage 2: wave handles e-cols [wave*32, wave*32+32) within each et
    const int ebase_w = wave * 32;
#pragma unroll 1
    for (int p = 0; p < 3; ++p) {            // et pairs: et = 2p, 2p+1
        bf16x8 w2f[2][2][4];                 // [e2][nf][ks], loop-invariant regs
#pragma unroll
        for (int e2 = 0; e2 < 2; ++e2)
#pragma unroll
            for (int nf = 0; nf < 2; ++nf) {
                int e = (2 * p + e2) * 128 + ebase_w + nf * 16 + lr;
                const unsigned short* wp = w2t + ((size_t)h * E_ + e) * A_ + lg * 8;
#pragma unroll
                for (int ks = 0; ks < 4; ++ks)
                    w2f[e2][nf][ks] = *(const bf16x8*)(wp + ks * 32);
            }
        f32x4 zz[4], oo[4];
#pragma unroll
        for (int q = 0; q < 4; ++q) { zz[q] = (f32x4)0.0f; oo[q] = (f32x4)0.0f; }

#pragma unroll 2
        for (int itr = 0; itr < 8; ++itr) {
            bf16x8 hfr[4];
#pragma unroll
            for (int ks = 0; ks < 4; ++ks) {
                int srow = itr * 16 + lr;
                hfr[ks] = *(const bf16x8*)((char*)hmt + ((srow * 256 + ks * 64 + lg * 16) ^ ((srow & 7) << 4)));
            }
            f32x4 lac[4];
#pragma unroll
            for (int q = 0; q < 4; ++q) lac[q] = (f32x4)0.0f;
#pragma unroll
            for (int ks = 0; ks < 4; ++ks)
#pragma unroll
                for (int e2 = 0; e2 < 2; ++e2)
#pragma unroll
                    for (int nf = 0; nf < 2; ++nf)
                        lac[e2 * 2 + nf] = __builtin_amdgcn_mfma_f32_16x16x32_bf16(
                            w2f[e2][nf][ks], hfr[ks], lac[e2 * 2 + nf], 0, 0, 0);
            // C layout: row(e-offset) = lg*4+j, col(s-offset) = lr
#pragma unroll
            for (int e2 = 0; e2 < 2; ++e2)
#pragma unroll
                for (int nf = 0; nf < 2; ++nf) {
                    int q = e2 * 2 + nf;
                    const float* xp = xb + (size_t)(itr * 16 + lr) * E_
                                    + (2 * p + e2) * 128 + ebase_w + nf * 16 + lg * 4;
                    f32x4 xv = *(const f32x4*)xp;
                    f32x4 pv;
#pragma unroll
                    for (int j = 0; j < 4; ++j) pv[j] = exp2f(lac[q][j]);
                    zz[q] += pv;
                    oo[q] += pv * xv;
                }
        }
        // reduce over the 16 s-columns (lr) within each lg group
#pragma unroll
        for (int q = 0; q < 4; ++q)
#pragma unroll
            for (int j = 0; j < 4; ++j) {
#pragma unroll
                for (int msk = 1; msk < 16; msk <<= 1) {
                    zz[q][j] += __shfl_xor(zz[q][j], msk);
                    oo[q][j] += __shfl_xor(oo[q][j], msk);
                }
            }
        if (lr == 0) {
#pragma unroll
            for (int e2 = 0; e2 < 2; ++e2)
#pragma unroll
                for (int nf = 0; nf < 2; ++nf) {
                    int q = e2 * 2 + nf;
                    int e = (2 * p + e2) * 128 + ebase_w + nf * 16 + lg * 4;
                    size_t base = ((size_t)(b * H_ + h) * E_ + e) * 32 + st;
#pragma unroll
                    for (int j = 0; j < 4; ++j) {
                        part_z[base + (size_t)j * 32] = zz[q][j];
                        part_o[base + (size_t)j * 32] = oo[q][j];
                    }
                }
        }
    }
}

// ---------------------------------------------------------------------------
// merge: out[b,h,e] = sum_st o / sum_st z   (st innermost -> contiguous reads)
// ---------------------------------------------------------------------------
__global__ __launch_bounds__(256) void k_merge(const float* __restrict__ part_z,
                                               const float* __restrict__ part_o,
                                               float* __restrict__ out) {
    int idx = blockIdx.x * 256 + threadIdx.x;
    if (idx >= B_ * H_ * E_) return;
    const float* pz = part_z + (size_t)idx * 32;
    const float* po = part_o + (size_t)idx * 32;
    float z = 0.f, o = 0.f;
#pragma unroll
    for (int q = 0; q < 8; ++q) {
        f32x4 a = *(const f32x4*)(pz + q * 4);
        f32x4 c = *(const f32x4*)(po + q * 4);
        z += (a[0] + a[1]) + (a[2] + a[3]);
        o += (c[0] + c[1]) + (c[2] + c[3]);
    }
    out[idx] = o / z;
}

// ---------------------------------------------------------------------------
extern "C" void kernel_launch(void* const* d_in, const int* in_sizes, int n_in,
                              void* d_out, int out_size, void* d_ws, size_t ws_size,
                              hipStream_t stream) {
    const float* x  = (const float*)d_in[0];
    const float* w1 = (const float*)d_in[1];
    const float* b1 = (const float*)d_in[2];
    const float* w2 = (const float*)d_in[3];
    // d_in[4] (b2) intentionally unused: constant over s, cancels in softmax
    float* out = (float*)d_out;

    char* ws = (char*)d_ws;
    float*          part_z = (float*)ws;                          // 6,291,456 B
    float*          part_o = (float*)(ws + 6291456);              // 6,291,456 B
    unsigned short* w1t    = (unsigned short*)(ws + 12582912);    //   786,432 B
    unsigned short* w2t    = (unsigned short*)(ws + 13369344);    //   786,432 B

    k_prep1<<<dim3(96),   256, 0, stream>>>(w1, w1t);
    k_prep2<<<dim3(96),   256, 0, stream>>>(w2, w2t);
    k_fused<<<dim3(2048), 256, 0, stream>>>(x, w1t, b1, w2t, part_z, part_o);
    k_merge<<<dim3(192),  256, 0, stream>>>(part_z, part_o, out);
}

// Round 6
// 547.136 us; speedup vs baseline: 1.1145x; 1.1145x over previous
//
#include <hip/hip_runtime.h>
#include <hip/hip_bf16.h>

#define B_ 16
#define S_ 4096
#define E_ 768
#define H_ 4
#define A_ 128

constexpr float ALPHA = 0.2f;
constexpr float LOG2E = 1.44269504088896340736f;

typedef __attribute__((ext_vector_type(4))) float f32x4;
typedef __attribute__((ext_vector_type(8))) short bf16x8;

__device__ __forceinline__ unsigned short f2bf(float f) {
    union { float f; unsigned int u; } v;
    v.f = f;
    unsigned int u = v.u;
    unsigned int r = (u + 0x7FFFu + ((u >> 16) & 1u)) >> 16;
    return (unsigned short)r;
}

__device__ __forceinline__ unsigned int pk2bf(float lo, float hi) {
    // compiles to v_cvt_pk_bf16_f32 (1 instr / 2 elems)
    __hip_bfloat162 h2 = __float22bfloat162_rn(make_float2(lo, hi));
    union { __hip_bfloat162 h; unsigned int u; } c;
    c.h = h2;
    return c.u;
}

// ---------------------------------------------------------------------------
// prep1: W1 [h][e][a] f32 -> W1T [h][a][e] bf16
// ---------------------------------------------------------------------------
__global__ __launch_bounds__(256) void k_prep1(const float* __restrict__ w1,
                                               unsigned short* __restrict__ w1t) {
    __shared__ unsigned short t[64 * 65];
    int bid = blockIdx.x;              // 96 = 4h * 12e * 2a
    int ta = bid & 1;
    int te = (bid >> 1) % 12;
    int h  = bid / 24;
    const float* src = w1 + (size_t)h * E_ * A_;
    unsigned short* dst = w1t + (size_t)h * A_ * E_;
    int tid = threadIdx.x;
#pragma unroll
    for (int it = 0; it < 16; ++it) {
        int idx = it * 256 + tid;
        int r = idx >> 6, c = idx & 63;
        t[r * 65 + c] = f2bf(src[(size_t)(te * 64 + r) * A_ + ta * 64 + c]);
    }
    __syncthreads();
#pragma unroll
    for (int it = 0; it < 16; ++it) {
        int idx = it * 256 + tid;
        int a = idx >> 6, e = idx & 63;
        dst[(size_t)(ta * 64 + a) * E_ + te * 64 + e] = t[e * 65 + a];
    }
}

// ---------------------------------------------------------------------------
// prep2: W2 [h][a][e] f32 -> W2T [h][e][a] bf16, pre-scaled by log2(e).
// b2 dropped: constant over s => cancels in softmax over s.
// ---------------------------------------------------------------------------
__global__ __launch_bounds__(256) void k_prep2(const float* __restrict__ w2,
                                               unsigned short* __restrict__ w2t) {
    __shared__ unsigned short t[64 * 65];
    int bid = blockIdx.x;              // 96
    int te = bid % 12;
    int ta = (bid / 12) & 1;
    int h  = bid / 24;
    const float* src = w2 + (size_t)h * A_ * E_;
    unsigned short* dst = w2t + (size_t)h * E_ * A_;
    int tid = threadIdx.x;
#pragma unroll
    for (int it = 0; it < 16; ++it) {
        int idx = it * 256 + tid;
        int r = idx >> 6, c = idx & 63;
        t[r * 65 + c] = f2bf(src[(size_t)(ta * 64 + r) * E_ + te * 64 + c] * LOG2E);
    }
    __syncthreads();
#pragma unroll
    for (int it = 0; it < 16; ++it) {
        int idx = it * 256 + tid;
        int e = idx >> 6, a = idx & 63;
        dst[(size_t)(te * 64 + e) * A_ + ta * 64 + a] = t[a * 65 + e];
    }
}

// ---------------------------------------------------------------------------
// stage1: Hm[b,h,s,a] = bf16(leakyrelu(x W1 + b1))
// 512 thr / 8 waves; tile 128s x 128a; BK=64; single-buffer LDS with
// T14 async-stage (global->reg early, reg->LDS after barrier).
// wave w: sw=w&1 (64-s half), aw=w>>1 (32-a quarter); acc 4sf x 2nf.
// grid: 2048 blocks, XCD-remapped, h innermost (x-tile L2 sharing).
// ---------------------------------------------------------------------------
__global__ __launch_bounds__(512, 4) void k_stage1(
    const float* __restrict__ x, const unsigned short* __restrict__ w1t,
    const float* __restrict__ b1, unsigned short* __restrict__ hm) {

    int bid = blockIdx.x;
    int wid = (bid & 7) * 256 + (bid >> 3);   // bijective: 2048 = 8*256
    const int h  = wid & 3;
    const int st = (wid >> 2) & 31;
    const int b  = wid >> 7;
    const int s0 = st * 128;

    const int tid = threadIdx.x;
    const int wv = tid >> 6, lane = tid & 63;
    const int lr = lane & 15, lg = lane >> 4;
    const int sw = wv & 1, aw = wv >> 1;

    __shared__ unsigned short bufA[128 * 64];  // x bf16 [s][e], swizzled, 16KB
    __shared__ unsigned short bufB[128 * 64];  // w1t bf16 [a][e], swizzled, 16KB

    const int ar = tid >> 2;   // staging row (0..127)
    const int ac = tid & 3;    // staging col group
    const float* xp = x + ((size_t)b * S_ + s0 + ar) * E_ + ac * 16;         // 4x f32x4 @ +l*4
    const unsigned short* wp = w1t + ((size_t)h * A_ + ar) * E_ + ac * 8;    // 2x bf16x8 @ +l*32

    f32x4 acc[4][2];
#pragma unroll
    for (int i = 0; i < 4; ++i)
#pragma unroll
        for (int j = 0; j < 2; ++j) acc[i][j] = (f32x4)0.0f;

    f32x4 xreg[4];
    bf16x8 wreg[2];
#pragma unroll
    for (int l = 0; l < 4; ++l) xreg[l] = *(const f32x4*)(xp + l * 4);
#pragma unroll
    for (int l = 0; l < 2; ++l) wreg[l] = *(const bf16x8*)(wp + l * 32);

#pragma unroll 1
    for (int ks = 0; ks < 12; ++ks) {
        if (ks) __syncthreads();               // prev tile fully consumed
        // reg -> LDS (converted), swizzled
#pragma unroll
        for (int l = 0; l < 4; ++l) {
            uint2 p;
            p.x = pk2bf(xreg[l][0], xreg[l][1]);
            p.y = pk2bf(xreg[l][2], xreg[l][3]);
            int byte = (ar * 128 + (ac * 4 + l) * 8) ^ ((ar & 7) << 4);
            *(uint2*)((char*)bufA + byte) = p;
        }
#pragma unroll
        for (int l = 0; l < 2; ++l) {
            int byte = (ar * 128 + (ac + l * 4) * 16) ^ ((ar & 7) << 4);
            *(bf16x8*)((char*)bufB + byte) = wreg[l];
        }
        __syncthreads();                       // tile ready
        if (ks < 11) {                         // prefetch next K-slab into regs
            const float* xq = xp + (ks + 1) * 64;
#pragma unroll
            for (int l = 0; l < 4; ++l) xreg[l] = *(const f32x4*)(xq + l * 4);
            const unsigned short* wq = wp + (ks + 1) * 64;
#pragma unroll
            for (int l = 0; l < 2; ++l) wreg[l] = *(const bf16x8*)(wq + l * 32);
        }
#pragma unroll
        for (int kk = 0; kk < 2; ++kk) {
            bf16x8 xf[4], wf[2];
#pragma unroll
            for (int sf = 0; sf < 4; ++sf) {
                int r = sw * 64 + sf * 16 + lr;
                xf[sf] = *(const bf16x8*)((char*)bufA + ((r * 128 + kk * 64 + lg * 16) ^ ((r & 7) << 4)));
            }
#pragma unroll
            for (int nf = 0; nf < 2; ++nf) {
                int r = aw * 32 + nf * 16 + lr;
                wf[nf] = *(const bf16x8*)((char*)bufB + ((r * 128 + kk * 64 + lg * 16) ^ ((r & 7) << 4)));
            }
#pragma unroll
            for (int sf = 0; sf < 4; ++sf)
#pragma unroll
                for (int nf = 0; nf < 2; ++nf)
                    acc[sf][nf] = __builtin_amdgcn_mfma_f32_16x16x32_bf16(
                        wf[nf], xf[sf], acc[sf][nf], 0, 0, 0);  // A=W1(a), B=x(s)
        }
    }

    // epilogue: C[row=a=lg*4+j, col=s=lr]; pack 4 a-contiguous bf16 -> 8B store
    const size_t hb = ((size_t)(b * H_ + h) * S_ + s0 + sw * 64) * A_ + aw * 32;
#pragma unroll
    for (int nf = 0; nf < 2; ++nf) {
        f32x4 bv = *(const f32x4*)(b1 + h * A_ + aw * 32 + nf * 16 + lg * 4);
#pragma unroll
        for (int sf = 0; sf < 4; ++sf) {
            f32x4 v = acc[sf][nf] + bv;
#pragma unroll
            for (int j = 0; j < 4; ++j) v[j] = v[j] >= 0.0f ? v[j] : ALPHA * v[j];
            uint2 p;
            p.x = pk2bf(v[0], v[1]);
            p.y = pk2bf(v[2], v[3]);
            *(uint2*)(hm + hb + (size_t)(sf * 16 + lr) * A_ + nf * 16 + lg * 4) = p;
        }
    }
}

// ---------------------------------------------------------------------------
// stage2: per block (b, h, 128-s chunk): hm tile -> LDS once (swizzled);
// et loop (6 x 128 e): W2 frags in regs; barrier-free streaming inner loop:
// 4 LDS reads + 8 MFMA + 8 exp2 + x f32x4 loads; per-et shuffle-reduce
// over the 16 s-columns; write (z,o) partials.
// ---------------------------------------------------------------------------
__global__ __launch_bounds__(256, 4) void k_stage2(
    const float* __restrict__ x, const unsigned short* __restrict__ hm,
    const unsigned short* __restrict__ w2t,
    float* __restrict__ part_z, float* __restrict__ part_o) {

    int bid = blockIdx.x;
    int wid = (bid & 7) * 256 + (bid >> 3);
    const int h  = wid & 3;
    const int sc = (wid >> 2) & 31;
    const int b  = wid >> 7;
    const int s0 = sc * 128;

    const int tid = threadIdx.x;
    const int wv = tid >> 6, lane = tid & 63;
    const int lr = lane & 15, lg = lane >> 4;

    __shared__ unsigned short hmt[128 * 128];  // [s][a] bf16, swizzled, 32KB

    // one-time staging of the hm tile
    {
        const unsigned short* hp = hm + ((size_t)(b * H_ + h) * S_ + s0) * A_;
        int r = tid >> 1;
        int c = tid & 1;
#pragma unroll
        for (int l = 0; l < 8; ++l) {
            int ch = c * 8 + l;
            bf16x8 v = *(const bf16x8*)(hp + (size_t)r * A_ + ch * 8);
            int byte = (r * 256 + ch * 16) ^ ((r & 7) << 4);
            *(bf16x8*)((char*)hmt + byte) = v;
        }
    }
    __syncthreads();

    const float* xb = x + ((size_t)b * S_ + s0) * E_;
    const unsigned short* w2h = w2t + (size_t)h * E_ * A_;
    const size_t pbase = (size_t)(b * H_ + h) * E_ * 32 + sc;

#pragma unroll 1
    for (int et = 0; et < 6; ++et) {
        const int e0 = et * 128 + wv * 32;     // this wave's 32-e slice
        bf16x8 w2f[2][4];
#pragma unroll
        for (int nf = 0; nf < 2; ++nf) {
            const unsigned short* q = w2h + (size_t)(e0 + nf * 16 + lr) * A_ + lg * 8;
#pragma unroll
            for (int k4 = 0; k4 < 4; ++k4) w2f[nf][k4] = *(const bf16x8*)(q + k4 * 32);
        }
        f32x4 zz[2], oo[2];
#pragma unroll
        for (int nf = 0; nf < 2; ++nf) { zz[nf] = (f32x4)0.0f; oo[nf] = (f32x4)0.0f; }

#pragma unroll 2
        for (int itr = 0; itr < 8; ++itr) {
            int srow = itr * 16 + lr;
            bf16x8 hf[4];
#pragma unroll
            for (int k4 = 0; k4 < 4; ++k4)
                hf[k4] = *(const bf16x8*)((char*)hmt +
                          ((srow * 256 + (k4 * 32 + lg * 8) * 2) ^ ((srow & 7) << 4)));
            f32x4 lac[2];
            lac[0] = (f32x4)0.0f; lac[1] = (f32x4)0.0f;
#pragma unroll
            for (int k4 = 0; k4 < 4; ++k4) {
                lac[0] = __builtin_amdgcn_mfma_f32_16x16x32_bf16(w2f[0][k4], hf[k4], lac[0], 0, 0, 0);
                lac[1] = __builtin_amdgcn_mfma_f32_16x16x32_bf16(w2f[1][k4], hf[k4], lac[1], 0, 0, 0);
            }
            // C: col(s)=lr, row(e)=lg*4+j ; logits already in log2 domain
#pragma unroll
            for (int nf = 0; nf < 2; ++nf) {
                const float* xq = xb + (size_t)srow * E_ + e0 + nf * 16 + lg * 4;
                f32x4 xv = *(const f32x4*)xq;
                f32x4 pv;
#pragma unroll
                for (int j = 0; j < 4; ++j) pv[j] = exp2f(lac[nf][j]);
                zz[nf] += pv;
                oo[nf] += pv * xv;
            }
        }
        // reduce the 16 s-columns (lr lanes within each lg group)
#pragma unroll
        for (int nf = 0; nf < 2; ++nf)
#pragma unroll
            for (int j = 0; j < 4; ++j) {
                float zv = zz[nf][j], ov = oo[nf][j];
#pragma unroll
                for (int msk = 1; msk < 16; msk <<= 1) {
                    zv += __shfl_xor(zv, msk);
                    ov += __shfl_xor(ov, msk);
                }
                if (lr == 0) {
                    int e = e0 + nf * 16 + lg * 4 + j;
                    part_z[pbase + (size_t)e * 32] = zv;
                    part_o[pbase + (size_t)e * 32] = ov;
                }
            }
    }
}

// ---------------------------------------------------------------------------
// merge: out[b,h,e] = sum_sc o / sum_sc z  (32 contiguous partials each)
// ---------------------------------------------------------------------------
__global__ __launch_bounds__(256) void k_merge(const float* __restrict__ part_z,
                                               const float* __restrict__ part_o,
                                               float* __restrict__ out) {
    int idx = blockIdx.x * 256 + threadIdx.x;
    if (idx >= B_ * H_ * E_) return;
    const float* pz = part_z + (size_t)idx * 32;
    const float* po = part_o + (size_t)idx * 32;
    float z = 0.f, o = 0.f;
#pragma unroll
    for (int q = 0; q < 8; ++q) {
        f32x4 a = *(const f32x4*)(pz + q * 4);
        f32x4 c = *(const f32x4*)(po + q * 4);
        z += (a[0] + a[1]) + (a[2] + a[3]);
        o += (c[0] + c[1]) + (c[2] + c[3]);
    }
    out[idx] = o / z;
}

// ---------------------------------------------------------------------------
extern "C" void kernel_launch(void* const* d_in, const int* in_sizes, int n_in,
                              void* d_out, int out_size, void* d_ws, size_t ws_size,
                              hipStream_t stream) {
    const float* x  = (const float*)d_in[0];
    const float* w1 = (const float*)d_in[1];
    const float* b1 = (const float*)d_in[2];
    const float* w2 = (const float*)d_in[3];
    // d_in[4] (b2) unused: constant over s, cancels in softmax
    float* out = (float*)d_out;

    char* ws = (char*)d_ws;
    unsigned short* hmw    = (unsigned short*)ws;                 // 67,108,864 B
    unsigned short* w1t    = (unsigned short*)(ws + 67108864);    //    786,432 B
    unsigned short* w2t    = (unsigned short*)(ws + 67895296);    //    786,432 B
    float*          part_z = (float*)(ws + 68681728);             //  6,291,456 B
    float*          part_o = (float*)(ws + 74973184);             //  6,291,456 B

    k_prep1 <<<dim3(96),   256, 0, stream>>>(w1, w1t);
    k_prep2 <<<dim3(96),   256, 0, stream>>>(w2, w2t);
    k_stage1<<<dim3(2048), 512, 0, stream>>>(x, w1t, b1, hmw);
    k_stage2<<<dim3(2048), 256, 0, stream>>>(x, hmw, w2t, part_z, part_o);
    k_merge <<<dim3(192),  256, 0, stream>>>(part_z, part_o, out);
}